// Round 6
// baseline (559.703 us; speedup 1.0000x reference)
//
#include <hip/hip_runtime.h>
#include <math.h>

typedef unsigned short u16;
typedef short s8v __attribute__((ext_vector_type(8)));   // 8 bf16 (4 VGPRs)
typedef float f4v __attribute__((ext_vector_type(4)));   // 4 fp32 acc

constexpr int Bv = 8, Tv = 2048, Cv = 768, Hv = 3072;
constexpr int BT = Bv * Tv;       // 16384 tokens
constexpr int BC = Bv * Cv;       // 6144 channels
constexpr int Lc = 128;           // WKV chunk length
constexpr int NCHK = Tv / Lc;     // 16 chunks
constexpr int KVS = 2304;         // fused k|v|sr row stride

__device__ __forceinline__ float b2f(u16 x) { return __uint_as_float(((unsigned)x) << 16); }
__device__ __forceinline__ u16 f2b(float f) {
    unsigned u = __float_as_uint(f);
    return (u16)((u + 0x7fffu + ((u >> 16) & 1u)) >> 16);   // RNE
}

#define GLOAD_LDS(g, l) __builtin_amdgcn_global_load_lds( \
    (const __attribute__((address_space(1))) void*)(g),    \
    (__attribute__((address_space(3))) void*)(l), 16, 0, 0)
#define BAR()  __builtin_amdgcn_s_barrier()

// ---------------- LayerNorm fp32 -> bf16 ----------------
__global__ __launch_bounds__(256) void ln_bf16(const float* __restrict__ x,
    const float* __restrict__ w, const float* __restrict__ b, u16* __restrict__ out)
{
    __shared__ float sh[8];
    int row = blockIdx.x;
    const float* xr = x + (size_t)row * Cv;
    float vals[3];
    float s = 0.f, s2 = 0.f;
#pragma unroll
    for (int i = 0; i < 3; i++) {
        float t = xr[threadIdx.x + 256 * i];
        vals[i] = t; s += t; s2 += t * t;
    }
#pragma unroll
    for (int off = 32; off > 0; off >>= 1) {
        s  += __shfl_down(s, off);
        s2 += __shfl_down(s2, off);
    }
    int wid = threadIdx.x >> 6;
    if ((threadIdx.x & 63) == 0) { sh[wid] = s; sh[4 + wid] = s2; }
    __syncthreads();
    if (threadIdx.x == 0) {
        sh[0] = sh[0] + sh[1] + sh[2] + sh[3];
        sh[4] = sh[4] + sh[5] + sh[6] + sh[7];
    }
    __syncthreads();
    float mean = sh[0] * (1.f / Cv);
    float var  = sh[4] * (1.f / Cv) - mean * mean;
    float rstd = rsqrtf(var + 1e-5f);
    u16* orow = out + (size_t)row * Cv;
#pragma unroll
    for (int i = 0; i < 3; i++) {
        int j = threadIdx.x + 256 * i;
        orow[j] = f2b((vals[i] - mean) * rstd * w[j] + b[j]);
    }
}

// ---------------- fp32 -> bf16 weight conversion ----------------
__global__ __launch_bounds__(256) void cvt_f2b(const float* __restrict__ s,
    u16* __restrict__ d, int n4)
{
    int i = blockIdx.x * 256 + threadIdx.x;
    if (i < n4) {
        float4 f = *(const float4*)(s + (size_t)i * 4);
        uint2 p;
        p.x = (unsigned)f2b(f.x) | ((unsigned)f2b(f.y) << 16);
        p.y = (unsigned)f2b(f.z) | ((unsigned)f2b(f.w) << 16);
        *(uint2*)(d + (size_t)i * 4) = p;
    }
}

// ---------------- 256x256 8-phase bf16 MFMA GEMM: out = A @ W^T (+ epilogue) ----------
// BM=BN=256, BK=64, 512 thr = 8 waves (2M x 4N); per-wave C = 128x64 (8x4 frags).
// LDS: 2 bufs x 4 planes {Ak0,Ak1,Bk0,Bk1} x [256 rows x 32 k] u16 = 128 KiB.
// 8 phases / 2 K-tiles; 1 half-tile staged per phase (2 x global_load_lds w16);
// counted vmcnt(6) at p4/p8 (3 half-tiles in flight); vmcnt(0) only in final pair.
// 16B-slot swizzle: slot ^= (row>>1)&3, pre-swizzled global source + swizzled ds_read.
// K % 128 == 0. grid = (M/256, N/256).
// EPI 0: bf16 out (sigmoid when bn>=sigoff); 2: bf16 relu^2; 3: f32 e0+b2f(e1)*acc; 4: f32 e0+acc
template<int EPI>
__global__ __launch_bounds__(512, 2) void gemm8p(const u16* __restrict__ A,
    const u16* __restrict__ W, void* __restrict__ outv, int K,
    int lda, int ldw, int ldc, int sigoff,
    const float* __restrict__ e0, const u16* __restrict__ e1)
{
    __shared__ u16 lds[2][4][8192];            // [buf][plane][256*32]
    const int tid = threadIdx.x;
    const int wv = tid >> 6, l = tid & 63;
    const int bm = blockIdx.x * 256, bn = blockIdx.y * 256;
    const int wr = wv >> 2, wc = wv & 3;       // 2M x 4N wave grid
    // ---- staging addresses (per-thread, source pre-swizzled) ----
    const int row0 = wv * 32 + (l >> 2);       // chunk = wv*128 + l; row = chunk>>2
    const int scol = (((l & 3) ^ ((row0 >> 1) & 3)) << 3);   // swizzled 16B slot (u16 units)
    const u16* srcA  = A + (size_t)(bm + row0) * lda + scol;
    const u16* srcA2 = srcA + (size_t)16 * lda;
    const u16* srcB  = W + (size_t)(bn + row0) * ldw + scol;
    const u16* srcB2 = srcB + (size_t)16 * ldw;
#define STAGE(buf, kt, half) { \
    const size_t kc = (size_t)(kt) * 64 + ((half) & 1) * 32; \
    GLOAD_LDS(((half) < 2 ? srcA  : srcB ) + kc, &lds[buf][half][wv * 1024]); \
    GLOAD_LDS(((half) < 2 ? srcA2 : srcB2) + kc, &lds[buf][half][wv * 1024 + 512]); }
    // ---- fragment read offsets (u16), swizzled ----
    const int swz   = ((l >> 4) ^ ((l >> 1) & 3)) << 3;
    const int abase = (wr * 128 + (l & 15)) * 32 + swz;      // + m*512
    const int bbase = (wc * 64 + (l & 15)) * 32 + swz;       // + n*512
#define RDA(buf, kh, mb) { \
    a[0] = *(const s8v*)&lds[buf][kh][abase + ((mb) + 0) * 512]; \
    a[1] = *(const s8v*)&lds[buf][kh][abase + ((mb) + 1) * 512]; \
    a[2] = *(const s8v*)&lds[buf][kh][abase + ((mb) + 2) * 512]; \
    a[3] = *(const s8v*)&lds[buf][kh][abase + ((mb) + 3) * 512]; }
#define RDB(dst, buf, kh) { \
    dst[0] = *(const s8v*)&lds[buf][2 + (kh)][bbase + 0 * 512]; \
    dst[1] = *(const s8v*)&lds[buf][2 + (kh)][bbase + 1 * 512]; \
    dst[2] = *(const s8v*)&lds[buf][2 + (kh)][bbase + 2 * 512]; \
    dst[3] = *(const s8v*)&lds[buf][2 + (kh)][bbase + 3 * 512]; }
#define MFMA16(MB, bf) { \
    __builtin_amdgcn_s_setprio(1); \
    _Pragma("unroll") \
    for (int mm = 0; mm < 4; mm++) \
        _Pragma("unroll") \
        for (int n = 0; n < 4; n++) \
            acc[(MB) + mm][n] = __builtin_amdgcn_mfma_f32_16x16x32_bf16( \
                a[mm], bf[n], acc[(MB) + mm][n], 0, 0, 0); \
    __builtin_amdgcn_s_setprio(0); }
#define VM6() asm volatile("s_waitcnt vmcnt(6)" ::: "memory")
#define VM0() asm volatile("s_waitcnt vmcnt(0)" ::: "memory")

    f4v acc[8][4] = {};
    const int NPR = K >> 7;                    // pairs of K-tiles
    // ---- prologue: tile0 all halves -> buf0; Bk0,Ak0,Bk1 of tile1 -> buf1 ----
    STAGE(0, 0, 0); STAGE(0, 0, 2); STAGE(0, 0, 1); STAGE(0, 0, 3);
    STAGE(1, 1, 2); STAGE(1, 1, 0); STAGE(1, 1, 3);
    VM6();                                     // tile0's 8 loads landed
    BAR();
    for (int pr = 0; pr < NPR; ++pr) {
        const int t = pr * 2;
        const bool lastp = (pr == NPR - 1);
        s8v a[4], bk0[4], bk1[4];
        // p1: k0 upper + Bk0; stage Ak1(t+1)
        RDA(0, 0, 0); RDB(bk0, 0, 0);
        STAGE(1, t + 1, 1);
        BAR(); MFMA16(0, bk0); BAR();
        // p2: k0 lower + Bk1; stage Bk0(t+2)
        RDA(0, 0, 4); RDB(bk1, 0, 1);
        if (!lastp) STAGE(0, t + 2, 2);
        BAR(); MFMA16(4, bk0); BAR();
        // p3: k1 upper; stage Ak0(t+2)
        RDA(0, 1, 0);
        if (!lastp) STAGE(0, t + 2, 0);
        BAR(); MFMA16(0, bk1); BAR();
        // p4: k1 lower; stage Bk1(t+2); GATE
        RDA(0, 1, 4);
        if (!lastp) { STAGE(0, t + 2, 3); VM6(); } else { VM0(); }
        BAR(); MFMA16(4, bk1); BAR();
        // p5: tile t+1 (buf1) k0 upper + Bk0; stage Ak1(t+2)
        RDA(1, 0, 0); RDB(bk0, 1, 0);
        if (!lastp) STAGE(0, t + 2, 1);
        BAR(); MFMA16(0, bk0); BAR();
        // p6: k0 lower + Bk1; stage Bk0(t+3)
        RDA(1, 0, 4); RDB(bk1, 1, 1);
        if (!lastp) STAGE(1, t + 3, 2);
        BAR(); MFMA16(4, bk0); BAR();
        // p7: k1 upper; stage Ak0(t+3)
        RDA(1, 1, 0);
        if (!lastp) STAGE(1, t + 3, 0);
        BAR(); MFMA16(0, bk1); BAR();
        // p8: k1 lower; stage Bk1(t+3); GATE
        RDA(1, 1, 4);
        if (!lastp) { STAGE(1, t + 3, 3); VM6(); }
        BAR(); MFMA16(4, bk1); BAR();
    }
#undef STAGE
#undef RDA
#undef RDB
#undef MFMA16
#undef VM6
#undef VM0
    // ---- epilogue ----
    const int r0 = bm + wr * 128 + ((l >> 4) << 2);
    const int c0 = bn + wc * 64 + (l & 15);
    const bool sig = (EPI == 0) && (bn >= sigoff);
#pragma unroll
    for (int mf = 0; mf < 8; mf++)
#pragma unroll
        for (int nf = 0; nf < 4; nf++)
#pragma unroll
            for (int i = 0; i < 4; i++) {
                size_t o = (size_t)(r0 + mf * 16 + i) * ldc + (c0 + nf * 16);
                float r = acc[mf][nf][i];
                if (EPI == 0) {
                    if (sig) r = 1.f / (1.f + __expf(-r));
                    ((u16*)outv)[o] = f2b(r);
                } else if (EPI == 2) {
                    float t = fmaxf(r, 0.f);
                    ((u16*)outv)[o] = f2b(t * t);
                } else if (EPI == 3) {
                    ((float*)outv)[o] = fmaf(b2f(e1[o]), r, e0[o]);
                } else if (EPI == 4) {
                    ((float*)outv)[o] = e0[o] + r;
                }
            }
}

// ---------------- WKV helpers ----------------
__device__ __forceinline__ void wkv_step(float& a, float& b, float& m,
                                         float w, float kt, float vt)
{
    float mm = fmaxf(m + w, kt);
    float e1 = __expf(m + w - mm);
    float e2 = __expf(kt - mm);
    a = e1 * a + e2 * vt;
    b = e1 * b + e2;
    m = mm;
}
__device__ __forceinline__ void wkv_merge(float& a, float& b, float& m,
                                          float shift, float a2, float b2, float m2)
{
    float ms = m + shift;
    float mm = fmaxf(ms, m2);
    float e1 = __expf(ms - mm);
    float e2 = __expf(m2 - mm);
    a = e1 * a + e2 * a2;
    b = e1 * b + e2 * b2;
    m = mm;
}

// ---------------- WKV pass 1: per-chunk fwd/bwd summaries ----------------
__global__ __launch_bounds__(256) void wkv_pass1(const u16* __restrict__ kvs,
    const float* __restrict__ decay, float* __restrict__ sums)
{
    int e = blockIdx.x * 256 + threadIdx.x;
    int idx = e % BC, ci = e / BC;
    int b = idx / Cv, c = idx % Cv;
    float w = decay[c] * (1.f / (float)Tv);
    size_t base = ((size_t)b * Tv + (size_t)ci * Lc) * KVS + c;
    const size_t P = (size_t)NCHK * BC;
    size_t so = (size_t)ci * BC + idx;
    float a = 0.f, bb = 0.f, m = -1e38f;
    for (int t = 0; t < Lc; t++) {
        size_t off = base + (size_t)t * KVS;
        wkv_step(a, bb, m, w, b2f(kvs[off]), b2f(kvs[off + 768]));
    }
    sums[0 * P + so] = a; sums[1 * P + so] = bb; sums[2 * P + so] = m;
    a = 0.f; bb = 0.f; m = -1e38f;
    for (int t = Lc - 1; t >= 0; t--) {
        size_t off = base + (size_t)t * KVS;
        wkv_step(a, bb, m, w, b2f(kvs[off]), b2f(kvs[off + 768]));
    }
    sums[3 * P + so] = a; sums[4 * P + so] = bb; sums[5 * P + so] = m;
}

// ---------------- WKV pass 2: scan chunk summaries -> exclusive checkpoints ----------------
__global__ __launch_bounds__(256) void wkv_pass2(const float* __restrict__ decay,
    const float* __restrict__ sums, float* __restrict__ chks)
{
    int idx = blockIdx.x * 256 + threadIdx.x;   // 0..BC-1
    int c = idx % Cv;
    float shift = decay[c] * (1.f / (float)Tv) * (float)Lc;
    const size_t P = (size_t)NCHK * BC;
    float a = 0.f, bb = 0.f, m = -1e38f;
    for (int ci = 0; ci < NCHK; ci++) {
        size_t so = (size_t)ci * BC + idx;
        chks[0 * P + so] = a; chks[1 * P + so] = bb; chks[2 * P + so] = m;
        wkv_merge(a, bb, m, shift, sums[0 * P + so], sums[1 * P + so], sums[2 * P + so]);
    }
    a = 0.f; bb = 0.f; m = -1e38f;
    for (int ci = NCHK - 1; ci >= 0; ci--) {
        size_t so = (size_t)ci * BC + idx;
        chks[3 * P + so] = a; chks[4 * P + so] = bb; chks[5 * P + so] = m;
        wkv_merge(a, bb, m, shift, sums[3 * P + so], sums[4 * P + so], sums[5 * P + so]);
    }
}

// ---------------- WKV pass 3: per-chunk combine, writes y*sr over k slot ----------------
__global__ __launch_bounds__(256) void wkv_pass3(u16* __restrict__ kvs,
    const float* __restrict__ decay, const float* __restrict__ first,
    const float* __restrict__ chks)
{
    int e = blockIdx.x * 256 + threadIdx.x;
    int idx = e % BC, ci = e / BC;
    int b = idx / Cv, c = idx % Cv;
    float w = decay[c] * (1.f / (float)Tv);
    float u = first[c] * (1.f / (float)Tv);
    const size_t P = (size_t)NCHK * BC;
    size_t so = (size_t)ci * BC + idx;
    size_t base = ((size_t)b * Tv + (size_t)ci * Lc) * KVS + c;
    float sa = chks[3 * P + so], sb2 = chks[4 * P + so], sm = chks[5 * P + so];
    float Ba[8], Bb[8], Bm[8];
#pragma unroll
    for (int si = 7; si >= 0; si--) {
        Ba[si] = sa; Bb[si] = sb2; Bm[si] = sm;
        for (int j = 15; j >= 0; j--) {
            size_t off = base + (size_t)(si * 16 + j) * KVS;
            wkv_step(sa, sb2, sm, w, b2f(kvs[off]), b2f(kvs[off + 768]));
        }
    }
    float fa = chks[0 * P + so], fb2 = chks[1 * P + so], fm = chks[2 * P + so];
#pragma unroll
    for (int si = 0; si < 8; si++) {
        float lk[16], lv[16], la[16], lb[16], lm[16];
        float ta = Ba[si], tb = Bb[si], tm = Bm[si];
#pragma unroll
        for (int j = 15; j >= 0; j--) {
            size_t off = base + (size_t)(si * 16 + j) * KVS;
            lk[j] = b2f(kvs[off]); lv[j] = b2f(kvs[off + 768]);
            la[j] = ta; lb[j] = tb; lm[j] = tm;
            wkv_step(ta, tb, tm, w, lk[j], lv[j]);
        }
#pragma unroll
        for (int j = 0; j < 16; j++) {
            float kk = lk[j] + u;
            float M  = fmaxf(fmaxf(fm, lm[j]), kk);
            float ef = __expf(fm - M);
            float eb = __expf(lm[j] - M);
            float ec = __expf(kk - M);
            float num = ef * fa + eb * la[j] + ec * lv[j];
            float den = ef * fb2 + eb * lb[j] + ec;
            size_t off = base + (size_t)(si * 16 + j) * KVS;
            kvs[off] = f2b(b2f(kvs[off + 1536]) * (num / den));  // y' = sr * y
            wkv_step(fa, fb2, fm, w, lk[j], lv[j]);
        }
    }
}

__global__ __launch_bounds__(256) void fill_signal(float* __restrict__ out, int n, float val)
{
    int i = blockIdx.x * 256 + threadIdx.x;
    if (i < n) out[i] = val;
}

extern "C" void kernel_launch(void* const* d_in, const int* in_sizes, int n_in,
                              void* d_out, int out_size, void* d_ws, size_t ws_size,
                              hipStream_t stream)
{
    const float* x     = (const float*)d_in[0];
    const float* ln1_w = (const float*)d_in[1];
    const float* ln1_b = (const float*)d_in[2];
    const float* ln2_w = (const float*)d_in[3];
    const float* ln2_b = (const float*)d_in[4];
    const float* decay = (const float*)d_in[5];
    const float* first = (const float*)d_in[6];
    const float* Wk_a  = (const float*)d_in[7];
    const float* Wv_a  = (const float*)d_in[8];
    const float* Wr_a  = (const float*)d_in[9];
    const float* Wo_a  = (const float*)d_in[10];
    const float* Wk_f  = (const float*)d_in[11];
    const float* Wv_f  = (const float*)d_in[12];
    const float* Wr_f  = (const float*)d_in[13];
    float* out = (float*)d_out;

    const size_t NCe = (size_t)BT * Cv;
    const size_t CC  = (size_t)Cv * Cv;
    const size_t HC  = (size_t)Hv * Cv;
    const size_t SUM = (size_t)6 * NCHK * BC;

    u16* hb    = (u16*)d_ws;                   // h / h2 (bf16)
    u16* kvs   = hb + NCe;                     // 3*NCe: k|v|sr interleaved (stride 2304)
    float* x1  = (float*)(kvs + 3 * NCe);      // fp32 x after attention
    u16* wKVR  = (u16*)(x1 + NCe);             // bf16 weights: [Wk;Wv;Wr] 2304x768
    u16* wOa   = wKVR + 3 * CC;
    u16* wRf   = wOa + CC;
    u16* wKf   = wRf + CC;
    u16* wVf   = wKf + HC;
    float* sums = (float*)(wVf + HC);
    float* chks = sums + SUM;
    u16* kfb_full = (u16*)(chks + SUM);
    size_t need_chunk = (size_t)((char*)kfb_full - (char*)d_ws);
    size_t need_full  = need_chunk + (size_t)BT * Hv * sizeof(u16);

    if (ws_size < need_chunk) {
        fill_signal<<<(int)((NCe + 255) / 256), 256, 0, stream>>>(out, (int)NCe, (float)(ws_size >> 20));
        return;
    }
    const bool full = (ws_size >= need_full);

    u16* gate = kvs;            // overlay: kvs dead after Wo-GEMM
    u16* kfb_c = kvs + NCe;     // 2*NCe = 8192*3072 (chunked FFN activation)

    dim3 blk(256);
    cvt_f2b<<<(int)(CC / 4 + 255) / 256, blk, 0, stream>>>(Wk_a, wKVR, (int)(CC / 4));
    cvt_f2b<<<(int)(CC / 4 + 255) / 256, blk, 0, stream>>>(Wv_a, wKVR + CC, (int)(CC / 4));
    cvt_f2b<<<(int)(CC / 4 + 255) / 256, blk, 0, stream>>>(Wr_a, wKVR + 2 * CC, (int)(CC / 4));
    cvt_f2b<<<(int)(CC / 4 + 255) / 256, blk, 0, stream>>>(Wo_a, wOa, (int)(CC / 4));
    cvt_f2b<<<(int)(CC / 4 + 255) / 256, blk, 0, stream>>>(Wr_f, wRf, (int)(CC / 4));
    cvt_f2b<<<(int)(HC / 4 + 255) / 256, blk, 0, stream>>>(Wk_f, wKf, (int)(HC / 4));
    cvt_f2b<<<(int)(HC / 4 + 255) / 256, blk, 0, stream>>>(Wv_f, wVf, (int)(HC / 4));

    dim3 g512(512);

    // 1. h = LN1(x)
    ln_bf16<<<BT, blk, 0, stream>>>(x, ln1_w, ln1_b, hb);
    // 2. fused [k|v|sr] = h @ [Wk;Wv;Wr]^T  (sigmoid on cols >= 1536)
    gemm8p<0><<<dim3(BT / 256, KVS / 256), g512, 0, stream>>>(
        hb, wKVR, kvs, Cv, Cv, Cv, KVS, 1536, nullptr, nullptr);
    // 3. bidirectional WKV (chunk-parallel); y*sr written over k slot
    wkv_pass1<<<(BC * NCHK) / 256, blk, 0, stream>>>(kvs, decay, sums);
    wkv_pass2<<<BC / 256, blk, 0, stream>>>(decay, sums, chks);
    wkv_pass3<<<(BC * NCHK) / 256, blk, 0, stream>>>(kvs, decay, first, chks);
    // 4. x1 = x + (sr*y) @ Wo^T
    gemm8p<4><<<dim3(BT / 256, Cv / 256), g512, 0, stream>>>(
        kvs, wOa, x1, Cv, KVS, Cv, Cv, 0, x, nullptr);
    // 5. h2 = LN2(x1)
    ln_bf16<<<BT, blk, 0, stream>>>(x1, ln2_w, ln2_b, hb);
    // 6. gate = sigmoid(h2 @ Wr_f^T)  (kvs now dead -> overlay)
    gemm8p<0><<<dim3(BT / 256, Cv / 256), g512, 0, stream>>>(
        hb, wRf, gate, Cv, Cv, Cv, Cv, -1, nullptr, nullptr);
    // 7. FFN
    if (full) {
        gemm8p<2><<<dim3(BT / 256, Hv / 256), g512, 0, stream>>>(
            hb, wKf, kfb_full, Cv, Cv, Cv, Hv, 0, nullptr, nullptr);
        gemm8p<3><<<dim3(BT / 256, Cv / 256), g512, 0, stream>>>(
            kfb_full, wVf, out, Hv, Hv, Hv, Cv, 0, x1, gate);
    } else {
        for (int j = 0; j < 2; j++) {
            size_t ro = (size_t)j * 8192;
            gemm8p<2><<<dim3(8192 / 256, Hv / 256), g512, 0, stream>>>(
                hb + ro * Cv, wKf, kfb_c, Cv, Cv, Cv, Hv, 0, nullptr, nullptr);
            gemm8p<3><<<dim3(8192 / 256, Cv / 256), g512, 0, stream>>>(
                kfb_c, wVf, out + ro * Cv, Hv, Hv, Hv, Cv, 0, x1 + ro * Cv, gate + ro * Cv);
        }
    }
}

// Round 7
// 528.952 us; speedup vs baseline: 1.0581x; 1.0581x over previous
//
#include <hip/hip_runtime.h>
#include <math.h>

typedef unsigned short u16;
typedef short s8v __attribute__((ext_vector_type(8)));   // 8 bf16 (4 VGPRs)
typedef float f4v __attribute__((ext_vector_type(4)));   // 4 fp32 acc

constexpr int Bv = 8, Tv = 2048, Cv = 768, Hv = 3072;
constexpr int BT = Bv * Tv;       // 16384 tokens
constexpr int BC = Bv * Cv;       // 6144 channels
constexpr int Lc = 128;           // WKV chunk length
constexpr int NCHK = Tv / Lc;     // 16 chunks
constexpr int KVS = 2304;         // fused k|v|sr row stride

__device__ __forceinline__ float b2f(u16 x) { return __uint_as_float(((unsigned)x) << 16); }
__device__ __forceinline__ u16 f2b(float f) {
    unsigned u = __float_as_uint(f);
    return (u16)((u + 0x7fffu + ((u >> 16) & 1u)) >> 16);   // RNE
}

#define GLOAD_LDS(g, l) __builtin_amdgcn_global_load_lds( \
    (const __attribute__((address_space(1))) void*)(g),    \
    (__attribute__((address_space(3))) void*)(l), 16, 0, 0)
#define BAR()  __builtin_amdgcn_s_barrier()
#define VM4()  asm volatile("s_waitcnt vmcnt(4)" ::: "memory")
#define VM0()  asm volatile("s_waitcnt vmcnt(0)" ::: "memory")

// ---------------- LayerNorm fp32 -> bf16 ----------------
__global__ __launch_bounds__(256) void ln_bf16(const float* __restrict__ x,
    const float* __restrict__ w, const float* __restrict__ b, u16* __restrict__ out)
{
    __shared__ float sh[8];
    int row = blockIdx.x;
    const float* xr = x + (size_t)row * Cv;
    float vals[3];
    float s = 0.f, s2 = 0.f;
#pragma unroll
    for (int i = 0; i < 3; i++) {
        float t = xr[threadIdx.x + 256 * i];
        vals[i] = t; s += t; s2 += t * t;
    }
#pragma unroll
    for (int off = 32; off > 0; off >>= 1) {
        s  += __shfl_down(s, off);
        s2 += __shfl_down(s2, off);
    }
    int wid = threadIdx.x >> 6;
    if ((threadIdx.x & 63) == 0) { sh[wid] = s; sh[4 + wid] = s2; }
    __syncthreads();
    if (threadIdx.x == 0) {
        sh[0] = sh[0] + sh[1] + sh[2] + sh[3];
        sh[4] = sh[4] + sh[5] + sh[6] + sh[7];
    }
    __syncthreads();
    float mean = sh[0] * (1.f / Cv);
    float var  = sh[4] * (1.f / Cv) - mean * mean;
    float rstd = rsqrtf(var + 1e-5f);
    u16* orow = out + (size_t)row * Cv;
#pragma unroll
    for (int i = 0; i < 3; i++) {
        int j = threadIdx.x + 256 * i;
        orow[j] = f2b((vals[i] - mean) * rstd * w[j] + b[j]);
    }
}

// ---------------- fp32 -> bf16 weight conversion ----------------
__global__ __launch_bounds__(256) void cvt_f2b(const float* __restrict__ s,
    u16* __restrict__ d, int n4)
{
    int i = blockIdx.x * 256 + threadIdx.x;
    if (i < n4) {
        float4 f = *(const float4*)(s + (size_t)i * 4);
        uint2 p;
        p.x = (unsigned)f2b(f.x) | ((unsigned)f2b(f.y) << 16);
        p.y = (unsigned)f2b(f.z) | ((unsigned)f2b(f.w) << 16);
        *(uint2*)(d + (size_t)i * 4) = p;
    }
}

// ---------------- 128x128 bf16 MFMA GEMM, 2 blocks/CU: out = A @ W^T (+ epilogue) ----
// BM=BN=128, BK=64, 256 thr = 4 waves (2x2); per-wave C = 64x64 (4x4 frags).
// LDS: 2 bufs x 4 planes {A_k0,A_k1,B_k0,B_k1} x [128 rows x 32 k] u16 = 64 KiB
//   -> 2 blocks/CU; inter-block overlap covers the ds_read/MFMA serialization.
// Per phase [t,kh]: 8 ds_read_b128 (A_kh,B_kh of buf t&1) | stage planes {A,B}_kh of
// tile t+1 into buf (t+1)&1 (4 gload_lds) | BAR | 16 MFMA | vmcnt(4) | BAR.
// Stage lands 2 phases before its read; last tile gates vmcnt(0).
// 16B-slot swizzle: slot ^= (row>>1)&3 (pre-swizzled source + swizzled ds_read).
// Grid: 1-D nb = (M/128)*ny, nb % 8 == 0; decode = XCD-chunk + y-fast (A streams once
// per XCD, B panel stays L2-resident). K % 64 == 0.
// EPI 0: bf16 out (sigmoid when bn>=sigoff); 3: f32 e0+b2f(e1)*acc; 4: f32 e0+acc;
// EPI 5: dual out: col<sigoff -> relu(acc)^2 bf16 to outv(ldc); else sigmoid bf16 to out2(ldc2).
template<int EPI>
__global__ __launch_bounds__(256, 2) void gemm128(const u16* __restrict__ A,
    const u16* __restrict__ W, void* __restrict__ outv, void* __restrict__ out2,
    int K, int lda, int ldw, int ldc, int ldc2, int ny, int sigoff,
    const float* __restrict__ e0, const u16* __restrict__ e1)
{
    __shared__ u16 lds[2][4][4096];            // [buf][plane][128*32]
    const int tid = threadIdx.x;
    const int wv = tid >> 6, l = tid & 63;
    const int nb = (int)gridDim.x, bid = (int)blockIdx.x;
    const int q = nb >> 3;
    const int sw = (bid & 7) * q + (bid >> 3);       // bijective XCD chunking (nb%8==0)
    const int bm = (sw / ny) * 128, bn = (sw % ny) * 128;  // y-fast within chunk
    const int wr = wv >> 1, wc = wv & 1;
    // ---- staging (source pre-swizzled; LDS written linearly by gload_lds) ----
    const int row0 = wv * 32 + (l >> 2);
    const int scol = ((l & 3) ^ ((l >> 3) & 3)) << 3;
    const u16* srcA = A + (size_t)(bm + row0) * lda + scol;
    const u16* srcB = W + (size_t)(bn + row0) * ldw + scol;
#define STG(buf, kt, kh) { \
    const size_t kc = (size_t)(kt) * 64 + (size_t)(kh) * 32; \
    GLOAD_LDS(srcA + kc,                    &lds[buf][kh][wv * 1024]); \
    GLOAD_LDS(srcA + kc + (size_t)16 * lda, &lds[buf][kh][wv * 1024 + 512]); \
    GLOAD_LDS(srcB + kc,                    &lds[buf][2 + (kh)][wv * 1024]); \
    GLOAD_LDS(srcB + kc + (size_t)16 * ldw, &lds[buf][2 + (kh)][wv * 1024 + 512]); }
    // ---- fragment read offsets (u16), swizzled ----
    const int swz = ((l >> 4) ^ ((l >> 1) & 3)) << 3;
    const int ab  = (wr * 64 + (l & 15)) * 32 + swz;
    const int bb  = (wc * 64 + (l & 15)) * 32 + swz;
#define RD(kh, pbuf) { \
    _Pragma("unroll") \
    for (int i = 0; i < 4; i++) { \
        a4[i] = *(const s8v*)&lds[pbuf][kh][ab + i * 512]; \
        b4[i] = *(const s8v*)&lds[pbuf][2 + (kh)][bb + i * 512]; } }
#define MF() { \
    __builtin_amdgcn_s_setprio(1); \
    _Pragma("unroll") \
    for (int mm = 0; mm < 4; mm++) \
        _Pragma("unroll") \
        for (int nn = 0; nn < 4; nn++) \
            acc[mm][nn] = __builtin_amdgcn_mfma_f32_16x16x32_bf16( \
                a4[mm], b4[nn], acc[mm][nn], 0, 0, 0); \
    __builtin_amdgcn_s_setprio(0); }

    f4v acc[4][4] = {};
    const int NKT = K >> 6;
    // prologue: all 4 planes of tile 0 -> buf0 (order: A0B0 then A1B1)
    STG(0, 0, 0); STG(0, 0, 1);
    VM4();                                    // A0,B0 landed
    BAR();
    for (int t = 0; t < NKT; ++t) {
        const int p = t & 1;
        const bool st = (t + 1) < NKT;
        s8v a4[4], b4[4];
        // phase kh=0
        RD(0, p);
        if (st) STG(p ^ 1, t + 1, 0);
        BAR();
        MF();
        if (st) VM4(); else VM0();
        BAR();
        // phase kh=1
        RD(1, p);
        if (st) STG(p ^ 1, t + 1, 1);
        BAR();
        MF();
        if (st) VM4();
        BAR();
    }
#undef STG
#undef RD
#undef MF
    // ---- epilogue: C row=(lane>>4)*4+i, col=lane&15 per 16x16 fragment ----
    const int r0 = bm + wr * 64 + ((l >> 4) << 2);
    const int c0 = bn + wc * 64 + (l & 15);
    const bool sig = (EPI == 0) && (bn >= sigoff);
#pragma unroll
    for (int mf = 0; mf < 4; mf++)
#pragma unroll
        for (int nf = 0; nf < 4; nf++)
#pragma unroll
            for (int i = 0; i < 4; i++) {
                const int row = r0 + mf * 16 + i;
                const int col = c0 + nf * 16;
                float r = acc[mf][nf][i];
                if (EPI == 0) {
                    if (sig) r = 1.f / (1.f + __expf(-r));
                    ((u16*)outv)[(size_t)row * ldc + col] = f2b(r);
                } else if (EPI == 3) {
                    size_t o = (size_t)row * ldc + col;
                    ((float*)outv)[o] = fmaf(b2f(e1[o]), r, e0[o]);
                } else if (EPI == 4) {
                    size_t o = (size_t)row * ldc + col;
                    ((float*)outv)[o] = e0[o] + r;
                } else if (EPI == 5) {
                    if (bn < sigoff) {
                        float t2 = fmaxf(r, 0.f);
                        ((u16*)outv)[(size_t)row * ldc + col] = f2b(t2 * t2);
                    } else {
                        float s = 1.f / (1.f + __expf(-r));
                        ((u16*)out2)[(size_t)row * ldc2 + (col - sigoff)] = f2b(s);
                    }
                }
            }
}

// ---------------- WKV helpers ----------------
__device__ __forceinline__ void wkv_step(float& a, float& b, float& m,
                                         float w, float kt, float vt)
{
    float mm = fmaxf(m + w, kt);
    float e1 = __expf(m + w - mm);
    float e2 = __expf(kt - mm);
    a = e1 * a + e2 * vt;
    b = e1 * b + e2;
    m = mm;
}
__device__ __forceinline__ void wkv_merge(float& a, float& b, float& m,
                                          float shift, float a2, float b2, float m2)
{
    float ms = m + shift;
    float mm = fmaxf(ms, m2);
    float e1 = __expf(ms - mm);
    float e2 = __expf(m2 - mm);
    a = e1 * a + e2 * a2;
    b = e1 * b + e2 * b2;
    m = mm;
}

// ---------------- WKV pass 1: per-chunk fwd/bwd summaries ----------------
__global__ __launch_bounds__(256) void wkv_pass1(const u16* __restrict__ kvs,
    const float* __restrict__ decay, float* __restrict__ sums)
{
    int e = blockIdx.x * 256 + threadIdx.x;
    int idx = e % BC, ci = e / BC;
    int b = idx / Cv, c = idx % Cv;
    float w = decay[c] * (1.f / (float)Tv);
    size_t base = ((size_t)b * Tv + (size_t)ci * Lc) * KVS + c;
    const size_t P = (size_t)NCHK * BC;
    size_t so = (size_t)ci * BC + idx;
    float a = 0.f, bb = 0.f, m = -1e38f;
    for (int t = 0; t < Lc; t++) {
        size_t off = base + (size_t)t * KVS;
        wkv_step(a, bb, m, w, b2f(kvs[off]), b2f(kvs[off + 768]));
    }
    sums[0 * P + so] = a; sums[1 * P + so] = bb; sums[2 * P + so] = m;
    a = 0.f; bb = 0.f; m = -1e38f;
    for (int t = Lc - 1; t >= 0; t--) {
        size_t off = base + (size_t)t * KVS;
        wkv_step(a, bb, m, w, b2f(kvs[off]), b2f(kvs[off + 768]));
    }
    sums[3 * P + so] = a; sums[4 * P + so] = bb; sums[5 * P + so] = m;
}

// ---------------- WKV pass 2: scan chunk summaries -> exclusive checkpoints ----------------
__global__ __launch_bounds__(256) void wkv_pass2(const float* __restrict__ decay,
    const float* __restrict__ sums, float* __restrict__ chks)
{
    int idx = blockIdx.x * 256 + threadIdx.x;   // 0..BC-1
    int c = idx % Cv;
    float shift = decay[c] * (1.f / (float)Tv) * (float)Lc;
    const size_t P = (size_t)NCHK * BC;
    float a = 0.f, bb = 0.f, m = -1e38f;
    for (int ci = 0; ci < NCHK; ci++) {
        size_t so = (size_t)ci * BC + idx;
        chks[0 * P + so] = a; chks[1 * P + so] = bb; chks[2 * P + so] = m;
        wkv_merge(a, bb, m, shift, sums[0 * P + so], sums[1 * P + so], sums[2 * P + so]);
    }
    a = 0.f; bb = 0.f; m = -1e38f;
    for (int ci = NCHK - 1; ci >= 0; ci--) {
        size_t so = (size_t)ci * BC + idx;
        chks[3 * P + so] = a; chks[4 * P + so] = bb; chks[5 * P + so] = m;
        wkv_merge(a, bb, m, shift, sums[3 * P + so], sums[4 * P + so], sums[5 * P + so]);
    }
}

// ---------------- WKV pass 3: per-chunk combine, writes y*sr over k slot ----------------
__global__ __launch_bounds__(256) void wkv_pass3(u16* __restrict__ kvs,
    const float* __restrict__ decay, const float* __restrict__ first,
    const float* __restrict__ chks)
{
    int e = blockIdx.x * 256 + threadIdx.x;
    int idx = e % BC, ci = e / BC;
    int b = idx / Cv, c = idx % Cv;
    float w = decay[c] * (1.f / (float)Tv);
    float u = first[c] * (1.f / (float)Tv);
    const size_t P = (size_t)NCHK * BC;
    size_t so = (size_t)ci * BC + idx;
    size_t base = ((size_t)b * Tv + (size_t)ci * Lc) * KVS + c;
    float sa = chks[3 * P + so], sb2 = chks[4 * P + so], sm = chks[5 * P + so];
    float Ba[8], Bb[8], Bm[8];
#pragma unroll
    for (int si = 7; si >= 0; si--) {
        Ba[si] = sa; Bb[si] = sb2; Bm[si] = sm;
        for (int j = 15; j >= 0; j--) {
            size_t off = base + (size_t)(si * 16 + j) * KVS;
            wkv_step(sa, sb2, sm, w, b2f(kvs[off]), b2f(kvs[off + 768]));
        }
    }
    float fa = chks[0 * P + so], fb2 = chks[1 * P + so], fm = chks[2 * P + so];
#pragma unroll
    for (int si = 0; si < 8; si++) {
        float lk[16], lv[16], la[16], lb[16], lm[16];
        float ta = Ba[si], tb = Bb[si], tm = Bm[si];
#pragma unroll
        for (int j = 15; j >= 0; j--) {
            size_t off = base + (size_t)(si * 16 + j) * KVS;
            lk[j] = b2f(kvs[off]); lv[j] = b2f(kvs[off + 768]);
            la[j] = ta; lb[j] = tb; lm[j] = tm;
            wkv_step(ta, tb, tm, w, lk[j], lv[j]);
        }
#pragma unroll
        for (int j = 0; j < 16; j++) {
            float kk = lk[j] + u;
            float M  = fmaxf(fmaxf(fm, lm[j]), kk);
            float ef = __expf(fm - M);
            float eb = __expf(lm[j] - M);
            float ec = __expf(kk - M);
            float num = ef * fa + eb * la[j] + ec * lv[j];
            float den = ef * fb2 + eb * lb[j] + ec;
            size_t off = base + (size_t)(si * 16 + j) * KVS;
            kvs[off] = f2b(b2f(kvs[off + 1536]) * (num / den));  // y' = sr * y
            wkv_step(fa, fb2, fm, w, lk[j], lv[j]);
        }
    }
}

__global__ __launch_bounds__(256) void fill_signal(float* __restrict__ out, int n, float val)
{
    int i = blockIdx.x * 256 + threadIdx.x;
    if (i < n) out[i] = val;
}

extern "C" void kernel_launch(void* const* d_in, const int* in_sizes, int n_in,
                              void* d_out, int out_size, void* d_ws, size_t ws_size,
                              hipStream_t stream)
{
    const float* x     = (const float*)d_in[0];
    const float* ln1_w = (const float*)d_in[1];
    const float* ln1_b = (const float*)d_in[2];
    const float* ln2_w = (const float*)d_in[3];
    const float* ln2_b = (const float*)d_in[4];
    const float* decay = (const float*)d_in[5];
    const float* first = (const float*)d_in[6];
    const float* Wk_a  = (const float*)d_in[7];
    const float* Wv_a  = (const float*)d_in[8];
    const float* Wr_a  = (const float*)d_in[9];
    const float* Wo_a  = (const float*)d_in[10];
    const float* Wk_f  = (const float*)d_in[11];
    const float* Wv_f  = (const float*)d_in[12];
    const float* Wr_f  = (const float*)d_in[13];
    float* out = (float*)d_out;

    const size_t NCe = (size_t)BT * Cv;
    const size_t CC  = (size_t)Cv * Cv;
    const size_t HC  = (size_t)Hv * Cv;
    const size_t SUM = (size_t)6 * NCHK * BC;

    u16* hb    = (u16*)d_ws;                   // h / h2 (bf16)
    u16* kvs   = hb + NCe;                     // 3*NCe: k|v|sr interleaved (stride 2304)
    float* x1  = (float*)(kvs + 3 * NCe);      // fp32 x after attention
    u16* wKVR  = (u16*)(x1 + NCe);             // bf16 [Wk;Wv;Wr] 2304x768
    u16* wOa   = wKVR + 3 * CC;                // 768x768
    u16* wUG   = wOa + CC;                     // [Wk_f; Wr_f] 3840x768
    u16* wVf   = wUG + HC + CC;                // 768x3072
    float* sums = (float*)(wVf + HC);
    float* chks = sums + SUM;
    u16* kfb_full = (u16*)(chks + SUM);
    size_t need_chunk = (size_t)((char*)kfb_full - (char*)d_ws);
    size_t need_full  = need_chunk + (size_t)BT * Hv * sizeof(u16);

    if (ws_size < need_chunk) {
        fill_signal<<<(int)((NCe + 255) / 256), 256, 0, stream>>>(out, (int)NCe, (float)(ws_size >> 20));
        return;
    }
    const bool full = (ws_size >= need_full);

    u16* gate  = kvs;            // overlay: kvs dead after Wo-GEMM
    u16* kfb_c = kvs + NCe;      // 2*NCe = 8192*3072 (chunked FFN activation)

    dim3 blk(256);
    cvt_f2b<<<(int)(CC / 4 + 255) / 256, blk, 0, stream>>>(Wk_a, wKVR, (int)(CC / 4));
    cvt_f2b<<<(int)(CC / 4 + 255) / 256, blk, 0, stream>>>(Wv_a, wKVR + CC, (int)(CC / 4));
    cvt_f2b<<<(int)(CC / 4 + 255) / 256, blk, 0, stream>>>(Wr_a, wKVR + 2 * CC, (int)(CC / 4));
    cvt_f2b<<<(int)(CC / 4 + 255) / 256, blk, 0, stream>>>(Wo_a, wOa, (int)(CC / 4));
    cvt_f2b<<<(int)(HC / 4 + 255) / 256, blk, 0, stream>>>(Wk_f, wUG, (int)(HC / 4));
    cvt_f2b<<<(int)(CC / 4 + 255) / 256, blk, 0, stream>>>(Wr_f, wUG + HC, (int)(CC / 4));
    cvt_f2b<<<(int)(HC / 4 + 255) / 256, blk, 0, stream>>>(Wv_f, wVf, (int)(HC / 4));

    // 1. h = LN1(x)
    ln_bf16<<<BT, blk, 0, stream>>>(x, ln1_w, ln1_b, hb);
    // 2. fused [k|v|sr] = h @ [Wk;Wv;Wr]^T  (sigmoid on cols >= 1536). grid 128*18=2304
    gemm128<0><<<dim3((BT / 128) * (KVS / 128)), blk, 0, stream>>>(
        hb, wKVR, kvs, nullptr, Cv, Cv, Cv, KVS, 0, KVS / 128, 1536, nullptr, nullptr);
    // 3. bidirectional WKV (chunk-parallel); y*sr written over k slot
    wkv_pass1<<<(BC * NCHK) / 256, blk, 0, stream>>>(kvs, decay, sums);
    wkv_pass2<<<BC / 256, blk, 0, stream>>>(decay, sums, chks);
    wkv_pass3<<<(BC * NCHK) / 256, blk, 0, stream>>>(kvs, decay, first, chks);
    // 4. x1 = x + (sr*y) @ Wo^T. grid 128*6=768
    gemm128<4><<<dim3((BT / 128) * (Cv / 128)), blk, 0, stream>>>(
        kvs, wOa, x1, nullptr, Cv, KVS, Cv, Cv, 0, Cv / 128, 0, x, nullptr);
    // 5. h2 = LN2(x1)
    ln_bf16<<<BT, blk, 0, stream>>>(x1, ln2_w, ln2_b, hb);
    // 6+7. fused FFN-up + gate: [kf | gate] = h2 @ [Wk_f; Wr_f]^T
    if (full) {
        gemm128<5><<<dim3((BT / 128) * ((Hv + Cv) / 128)), blk, 0, stream>>>(
            hb, wUG, kfb_full, gate, Cv, Cv, Cv, Hv, Cv, (Hv + Cv) / 128, Hv, nullptr, nullptr);
        gemm128<3><<<dim3((BT / 128) * (Cv / 128)), blk, 0, stream>>>(
            kfb_full, wVf, out, nullptr, Hv, Hv, Hv, Cv, 0, Cv / 128, 0, x1, gate);
    } else {
        for (int j = 0; j < 2; j++) {
            size_t ro = (size_t)j * 8192;
            gemm128<5><<<dim3((8192 / 128) * ((Hv + Cv) / 128)), blk, 0, stream>>>(
                hb + ro * Cv, wUG, kfb_c, gate + ro * Cv, Cv, Cv, Cv, Hv, Cv,
                (Hv + Cv) / 128, Hv, nullptr, nullptr);
            gemm128<3><<<dim3((8192 / 128) * (Cv / 128)), blk, 0, stream>>>(
                kfb_c, wVf, out + ro * Cv, nullptr, Hv, Hv, Hv, Cv, 0, Cv / 128, 0,
                x1 + ro * Cv, gate + ro * Cv);
        }
    }
}